// Round 7
// baseline (151.573 us; speedup 1.0000x reference)
//
#include <hip/hip_runtime.h>

typedef __attribute__((ext_vector_type(8))) short short8;
typedef __attribute__((ext_vector_type(4))) float floatx4;
typedef __attribute__((ext_vector_type(4))) unsigned short ushortx4;
typedef __attribute__((ext_vector_type(8))) unsigned short ushortx8;
typedef unsigned int u32;
typedef __attribute__((ext_vector_type(4))) u32 u32x4;

#define MFMA_K32(A, B, C) __builtin_amdgcn_mfma_f32_16x16x32_bf16(A, B, C, 0, 0, 0)

#if __has_builtin(__builtin_amdgcn_exp2f)
#define EXP2(x) __builtin_amdgcn_exp2f(x)
#else
#define EXP2(x) exp2f(x)
#endif

// gfx9 waitcnt imm: vmcnt[3:0] | expcnt<<4 | lgkmcnt<<8 | vmcnt[5:4]<<14 (exp/lgkm = no-wait)
#define WAIT_VM12() __builtin_amdgcn_s_waitcnt(0x0F7C)  // keep 12 newest in flight
#define WAIT_VM8() __builtin_amdgcn_s_waitcnt(0x0F78)
#define WAIT_VM0() __builtin_amdgcn_s_waitcnt(0x0F70)
#define SB0() __builtin_amdgcn_sched_barrier(0)

__device__ __forceinline__ unsigned short f2bf(float f) {  // RNE
  u32 u = __builtin_bit_cast(u32, f);
  u += 0x7FFFu + ((u >> 16) & 1u);
  return (unsigned short)(u >> 16);
}
// async 16B/lane global->LDS: lds dst = wave-uniform base + lane*16
__device__ __forceinline__ void load_lds16(const void* g, void* l) {
  __builtin_amdgcn_global_load_lds((const __attribute__((address_space(1))) u32*)g,
                                   (__attribute__((address_space(3))) u32*)l, 16, 0, 0);
}

// Prep (512 blocks): K slab fp32->bf16 (plain [b][key][d]) + V 64-key tile ->
// vt[b][t*4+w][d][32key] bf16 (32-key wave windows, natural key order inside window).
__global__ __launch_bounds__(256) void prep_kv(
    const float* __restrict__ k, const float* __restrict__ v,
    unsigned short* __restrict__ kb, unsigned short* __restrict__ vt) {
  __shared__ float tileT[64 * 68];  // [d][key-in-64]
  const int blk = blockIdx.x, tid = threadIdx.x;
  size_t base = (size_t)blk * 4096 + tid * 4;
#pragma unroll
  for (int i = 0; i < 4; i++) {
    size_t off = base + (size_t)i * 1024;
    floatx4 f = *(const floatx4*)(k + off);
    ushortx4 h;
    h[0] = f2bf(f[0]); h[1] = f2bf(f[1]); h[2] = f2bf(f[2]); h[3] = f2bf(f[3]);
    *(ushortx4*)(kb + off) = h;
  }
  // V: block = (b, h) covering keys [h*64, h*64+64) -> windows (t=h>>1, w=2*(h&1)+s)
  const int b = blk >> 6, h = blk & 63;
  const int r = tid >> 2, c4 = (tid & 3) * 16;
  const float* vp = v + ((size_t)b * 4096 + h * 64 + r) * 64 + c4;
#pragma unroll
  for (int i = 0; i < 4; i++) {
    floatx4 f = *(const floatx4*)(vp + i * 4);
#pragma unroll
    for (int j = 0; j < 4; j++) tileT[(c4 + i * 4 + j) * 68 + r] = f[j];
  }
  __syncthreads();
  const int d = tid >> 2, g = tid & 3;
  unsigned short* vb = vt + (size_t)b * 262144 + ((h >> 1) * 4 + (h & 1) * 2) * 2048;
#pragma unroll
  for (int s = 0; s < 2; s++) {
    const float* src = tileT + d * 68 + s * 32 + g * 8;
    floatx4 f0 = *(const floatx4*)src;
    floatx4 f1 = *(const floatx4*)(src + 4);
    ushortx8 hh;
#pragma unroll
    for (int j = 0; j < 4; j++) { hh[j] = f2bf(f0[j]); hh[4 + j] = f2bf(f1[j]); }
    *(ushortx8*)(vb + s * 2048 + d * 32 + g * 8) = hh;
  }
}

// Attention, KEY-SPLIT by NSPLIT (grid = 512*NSPLIT blocks x 256 thr, 4 waves).
// Round-6 lesson: 512-reg/SIMD file -> round-0's ~180 regs/wave = 2 waves/SIMD;
// +64-reg kf prefetch halved residency (9.6% occ). This round goes the OTHER way:
// trim to <=170 total (l on VALU: -o_l[16acc] -ones8[4] +l_acc[4]) AND 3 LDS bufs
// (48 KB -> 3 blocks/CU LDS-wise) AND grid 1024 via key-split (Q-split doubles K/V
// L2 traffic -- round-4 lesson; key-split keeps it constant, halves combine by
// addition since softmax is unnormalized-exp). Schedule = round-0 depth on mod-3
// rotation (round-3-verified): stage 2 ahead, steady wait vmcnt(12), V reg
// ping-pong 1 ahead. NO min-waves hint (rounds 1-3: caps below demand spill).
// Half 0 -> raw partial to out; half 1 -> pbuf; l -> lws; finalize merges.
// S^T=K*Q^T -> C-layout==PV B-frag layout -> P register-direct.
template <int NSPLIT>
__global__ __launch_bounds__(256) void attn(
    const float* __restrict__ q, const unsigned short* __restrict__ kb,
    const unsigned short* __restrict__ vt, const float* __restrict__ mask,
    float* __restrict__ out, float* __restrict__ pbuf, float* __restrict__ lws) {
  constexpr int NT = 32 / NSPLIT;  // K-tiles per block
  // loop: 4 waves x 3 K bufs x 2048 ushorts = 49152 B (wave-private)
  // epilogue reuses: obuf 2x[64][72] fp32 + lbuf [4][64] = 37888 B
  __shared__ __align__(16) char smem_raw[49152];
  unsigned short* smem = (unsigned short*)smem_raw;
  const int tid = threadIdx.x;
  const int wave = tid >> 6, lane = tid & 63;
  const int c = lane & 15, quad = lane >> 4;
  const int blk = blockIdx.x & 511;
  const int kh = blockIdx.x >> 9;  // key-half (always 0 when NSPLIT=1)
  const int b = blk & 7, qt = blk >> 3;  // blk%8=batch -> per-XCD L2 locality
  const int q0 = qt * 64;

  const unsigned short* kB = kb + (size_t)b * (4096 * 64);
  const unsigned short* vtB = vt + (size_t)b * 262144;

  // Q B-frags (B[k=d=kc*32+quad*8+j][n=q=c]), loop-invariant; fold (1/8)*log2(e)
  const float qscale = 0.18033688011112042f;
  short8 qf[4][2];
#pragma unroll
  for (int nt = 0; nt < 4; nt++)
#pragma unroll
    for (int kc = 0; kc < 2; kc++) {
      const float* qp = q + ((size_t)b * 4096 + q0 + nt * 16 + c) * 64 + kc * 32 + quad * 8;
      floatx4 f0 = *(const floatx4*)qp;
      floatx4 f1 = *(const floatx4*)(qp + 4);
      short8 s;
#pragma unroll
      for (int j = 0; j < 4; j++) {
        s[j] = (short)f2bf(f0[j] * qscale);
        s[4 + j] = (short)f2bf(f1[j] * qscale);
      }
      qf[nt][kc] = s;
    }

  floatx4 o[4][4];  // O^T[d=mt*16+quad*4+r][q=nt*16+c]
  float l_acc[4];   // per-lane softmax-denom partial (keys quad*8+j, col q=nt*16+c)
#pragma unroll
  for (int mt = 0; mt < 4; mt++)
#pragma unroll
    for (int nt = 0; nt < 4; nt++) o[mt][nt] = (floatx4){0.f, 0.f, 0.f, 0.f};
#pragma unroll
  for (int nt = 0; nt < 4; nt++) l_acc[nt] = 0.f;

  const int r8 = lane >> 3, cs8 = lane & 7;
  const int klane = (r8 >> 2) * 8 + (r8 & 3);  // row-permutation: C row (quad,r) -> key quad*8+r
  unsigned short* wbase = smem + wave * 6144;  // 3 bufs x 2048
  // monotone staging/load pointers (advance 8192 per tile)
  const unsigned short* kstage = kB + (size_t)(kh * NT) * 8192 +
                                 (size_t)(wave * 32 + klane) * 64 + (cs8 ^ r8) * 8;
  const unsigned short* vload = vtB + (size_t)(kh * NT) * 8192 + wave * 2048 + c * 32 + quad * 8;

  auto stageK = [&](u32 off) {  // 4KB: tileA (keys {q8+0..3}) | tileB ({q8+4..7})
    unsigned short* Kd = wbase + off;
    load_lds16(kstage, Kd);                    // tileA rows 0-7   (key off  0)
    load_lds16(kstage + 16 * 64, Kd + 512);    // tileA rows 8-15  (key off 16)
    load_lds16(kstage + 4 * 64, Kd + 1024);    // tileB rows 0-7   (key off  4)
    load_lds16(kstage + 20 * 64, Kd + 1536);   // tileB rows 8-15  (key off 20)
    kstage += 8192;
  };
  auto loadV = [&](u32x4* vv) {  // 4 x 1KB-coalesced register loads
#pragma unroll
    for (int mt = 0; mt < 4; mt++) vv[mt] = *(const u32x4*)(vload + mt * 512);
    vload += 8192;
  };

  auto compute = [&](u32 off, const u32x4* vv) {
    const unsigned short* Kbuf = wbase + off;
    short8 kfA[2], kfB[2];  // A[m=key][k=d]; phys slot = (kc*4+quad)^(c&7)
#pragma unroll
    for (int kc = 0; kc < 2; kc++) {
      const int sl = ((kc * 4 + quad) ^ (c & 7)) * 8;
      kfA[kc] = *(const short8*)(Kbuf + c * 64 + sl);
      kfB[kc] = *(const short8*)(Kbuf + 1024 + c * 64 + sl);
    }
#pragma unroll
    for (int nt = 0; nt < 4; nt++) {
      floatx4 sA = (floatx4){0.f, 0.f, 0.f, 0.f}, sB = sA;
      sA = MFMA_K32(kfA[0], qf[nt][0], sA);
      sA = MFMA_K32(kfA[1], qf[nt][1], sA);
      sB = MFMA_K32(kfB[0], qf[nt][0], sB);
      sB = MFMA_K32(kfB[1], qf[nt][1], sB);
      // P^T[key=quad*8+j][q=nt*16+c]: A gives j=0..3, B gives j=4..7 (row-permuted staging)
      float eA0 = EXP2(sA[0]), eA1 = EXP2(sA[1]), eA2 = EXP2(sA[2]), eA3 = EXP2(sA[3]);
      float eB0 = EXP2(sB[0]), eB1 = EXP2(sB[1]), eB2 = EXP2(sB[2]), eB3 = EXP2(sB[3]);
      l_acc[nt] += ((eA0 + eA1) + (eA2 + eA3)) + ((eB0 + eB1) + (eB2 + eB3));
      u32 a0 = __builtin_bit_cast(u32, eA0), a1 = __builtin_bit_cast(u32, eA1);
      u32 a2 = __builtin_bit_cast(u32, eA2), a3 = __builtin_bit_cast(u32, eA3);
      u32 b0 = __builtin_bit_cast(u32, eB0), b1 = __builtin_bit_cast(u32, eB1);
      u32 b2 = __builtin_bit_cast(u32, eB2), b3 = __builtin_bit_cast(u32, eB3);
      u32x4 pw = {__builtin_amdgcn_perm(a1, a0, 0x07060302u),
                  __builtin_amdgcn_perm(a3, a2, 0x07060302u),
                  __builtin_amdgcn_perm(b1, b0, 0x07060302u),
                  __builtin_amdgcn_perm(b3, b2, 0x07060302u)};
      short8 pf = __builtin_bit_cast(short8, pw);  // K32 B-frag: B[k=quad*8+j][n=c]
#pragma unroll
      for (int mt = 0; mt < 4; mt++)
        o[mt][nt] = MFMA_K32(__builtin_bit_cast(short8, vv[mt]), pf, o[mt][nt]);
    }
  };

  u32x4 vvA[4], vvB[4];
  stageK(0);     // tile 0 -> buf0
  loadV(vvA);    // V0
  stageK(2048);  // tile 1 -> buf1
  // Invariant before phase t: outstanding (oldest first) = [K(t), V(t), K(t+1)] = 12.
  // Phase t: issue V(t+1), K(t+2) -> 20; vmcnt(12) completes K(t), V(t): exactly what
  // compute(t) needs; K(t+1), V(t+1), K(t+2) stay in flight (round-0 depth). In pB,
  // stageK into buf(t%3) overwrites the buffer consumed in pA: its ds_reads returned
  // (lgkmcnt before pA's MFMAs) before this DMA issues -- program order, round-3-verified.
  u32 bo = 0;  // byte.. ushort offset of buf(t%3): cycles 0 -> 4096 -> 2048 -> 0
#pragma unroll 1
  for (int it = 0; it < (NT - 2) / 2; ++it) {
    u32 s1 = bo + 4096; if (s1 >= 6144) s1 -= 6144;   // buf((t+2)%3)
    loadV(vvB); stageK(s1);
    WAIT_VM12(); SB0();
    compute(bo, vvA); SB0();

    u32 b1 = bo + 2048; if (b1 >= 6144) b1 -= 6144;   // buf((t+1)%3)
    loadV(vvA); stageK(bo);                            // tile t+3 -> buf((t+3)%3)=buf(t%3)
    WAIT_VM12(); SB0();
    compute(b1, vvB); SB0();
    bo = s1;
  }
  // tail: phases NT-2, NT-1. Outstanding = [K(NT-2), V(NT-2), K(NT-1)].
  loadV(vvB);         // V(NT-1) -> 16 outstanding
  WAIT_VM8(); SB0();  // completes K(NT-2), V(NT-2)
  compute(bo, vvA); SB0();
  WAIT_VM0(); SB0();  // completes K(NT-1), V(NT-1)
  u32 bl = bo + 2048; if (bl >= 6144) bl -= 6144;
  compute(bl, vvB);

  // per-wave l: sum across quads (lanes c, c+16, c+32, c+48)
  float lw[4];
#pragma unroll
  for (int nt = 0; nt < 4; nt++) {
    float l = l_acc[nt];
    l += __shfl_xor(l, 16);
    l += __shfl_xor(l, 32);
    lw[nt] = l;
  }

  // ---- merge 4 wave-partials (first barriers since loop start) ----
  __syncthreads();
  float* obuf = (float*)smem_raw;  // 2 x [64 q][72]
  float* lbuf = obuf + 9216;       // [4 waves][64 q]
  if (lane < 16) {
#pragma unroll
    for (int nt = 0; nt < 4; nt++) lbuf[wave * 64 + nt * 16 + c] = lw[nt];
  }
  if (wave < 2) {
    float* ob = obuf + wave * 4608;
#pragma unroll
    for (int mt = 0; mt < 4; mt++)
#pragma unroll
      for (int nt = 0; nt < 4; nt++)
        *(floatx4*)(ob + (nt * 16 + c) * 72 + mt * 16 + quad * 4) = o[mt][nt];
  }
  __syncthreads();
  if (wave >= 2) {
    float* ob = obuf + (wave - 2) * 4608;
#pragma unroll
    for (int mt = 0; mt < 4; mt++)
#pragma unroll
      for (int nt = 0; nt < 4; nt++) {
        float* a = ob + (nt * 16 + c) * 72 + mt * 16 + quad * 4;
        floatx4 cur = *(floatx4*)a;
        *(floatx4*)a = cur + o[mt][nt];
      }
  }
  __syncthreads();

  const int row = tid >> 2, dg = (tid & 3) * 16;
  const float lsum = lbuf[row] + lbuf[64 + row] + lbuf[128 + row] + lbuf[192 + row];
  if constexpr (NSPLIT == 1) {
    // out = O/l * mask, coalesced float4 stores
    const float sc = mask[b * 4096 + q0 + row] / lsum;
    float* op = out + ((size_t)b * 4096 + q0 + row) * 64 + dg;
#pragma unroll
    for (int i = 0; i < 4; i++) {
      floatx4 a = *(const floatx4*)(obuf + row * 72 + dg + i * 4);
      floatx4 b2 = *(const floatx4*)(obuf + 4608 + row * 72 + dg + i * 4);
      *(floatx4*)(op + i * 4) = (a + b2) * sc;
    }
  } else {
    // raw partial: half 0 -> out slot, half 1 -> pbuf slot; l -> lws
    float* dst = (kh ? (pbuf + (size_t)blk * 4096)
                     : (out + ((size_t)b * 4096 + q0) * 64)) + row * 64 + dg;
#pragma unroll
    for (int i = 0; i < 4; i++) {
      floatx4 a = *(const floatx4*)(obuf + row * 72 + dg + i * 4);
      floatx4 b2 = *(const floatx4*)(obuf + 4608 + row * 72 + dg + i * 4);
      *(floatx4*)(dst + i * 4) = a + b2;
    }
    if ((tid & 3) == 0) lws[blk * 128 + kh * 64 + row] = lsum;
  }
}

// Merge the two key-halves: out = (P0 + P1) * mask / (l0 + l1). 512 blocks.
__global__ __launch_bounds__(256) void finalize(
    const float* __restrict__ mask, const float* __restrict__ pbuf,
    const float* __restrict__ lws, float* __restrict__ out) {
  const int blk = blockIdx.x;
  const int b = blk & 7, qt = blk >> 3;
  const int row = threadIdx.x >> 2, dg = (threadIdx.x & 3) * 16;
  const float l = lws[blk * 128 + row] + lws[blk * 128 + 64 + row];
  const float sc = mask[b * 4096 + qt * 64 + row] / l;
  float* op = out + ((size_t)b * 4096 + qt * 64 + row) * 64 + dg;
  const float* pp = pbuf + (size_t)blk * 4096 + row * 64 + dg;
#pragma unroll
  for (int i = 0; i < 4; i++)
    *(floatx4*)(op + i * 4) =
        (*(const floatx4*)(op + i * 4) + *(const floatx4*)(pp + i * 4)) * sc;
}

extern "C" void kernel_launch(void* const* d_in, const int* in_sizes, int n_in,
                              void* d_out, int out_size, void* d_ws, size_t ws_size,
                              hipStream_t stream) {
  const float* q = (const float*)d_in[0];
  const float* k = (const float*)d_in[1];
  const float* v = (const float*)d_in[2];
  const float* mask = (const float*)d_in[3];
  unsigned short* kb = (unsigned short*)d_ws;  // 4 MB
  unsigned short* vt = kb + 8 * 4096 * 64;     // 4 MB
  const size_t base = (size_t)8 * 1024 * 1024;
  const size_t need = base + (size_t)512 * 4096 * 4 + (size_t)512 * 128 * 4;  // 16.25 MB
  prep_kv<<<512, 256, 0, stream>>>(k, v, kb, vt);
  if (ws_size >= need) {
    float* pbuf = (float*)((char*)d_ws + base);  // 8 MB half-1 partials
    float* lws = pbuf + (size_t)512 * 4096;      // 256 KB per-row l, both halves
    attn<2><<<1024, 256, 0, stream>>>(q, kb, vt, mask, (float*)d_out, pbuf, lws);
    finalize<<<512, 256, 0, stream>>>(mask, pbuf, lws, (float*)d_out);
  } else {
    attn<1><<<512, 256, 0, stream>>>(q, kb, vt, mask, (float*)d_out,
                                     (float*)d_out, (float*)d_out);
  }
}

// Round 8
// 120.823 us; speedup vs baseline: 1.2545x; 1.2545x over previous
//
#include <hip/hip_runtime.h>

typedef __attribute__((ext_vector_type(8))) short short8;
typedef __attribute__((ext_vector_type(4))) float floatx4;
typedef __attribute__((ext_vector_type(4))) unsigned short ushortx4;
typedef __attribute__((ext_vector_type(8))) unsigned short ushortx8;
typedef unsigned int u32;
typedef __attribute__((ext_vector_type(2))) u32 u32x2;
typedef __attribute__((ext_vector_type(4))) u32 u32x4;

#define MFMA_K32(A, B, C) __builtin_amdgcn_mfma_f32_16x16x32_bf16(A, B, C, 0, 0, 0)

#if __has_builtin(__builtin_amdgcn_exp2f)
#define EXP2(x) __builtin_amdgcn_exp2f(x)
#else
#define EXP2(x) exp2f(x)
#endif

// gfx9 waitcnt imm: vmcnt[3:0] | expcnt<<4 | lgkmcnt<<8 | vmcnt[5:4]<<14 (exp/lgkm = no-wait)
#define WAIT_VM12() __builtin_amdgcn_s_waitcnt(0x0F7C)  // keep 12 newest in flight
#define WAIT_VM8() __builtin_amdgcn_s_waitcnt(0x0F78)
#define WAIT_VM0() __builtin_amdgcn_s_waitcnt(0x0F70)
#define SB0() __builtin_amdgcn_sched_barrier(0)

__device__ __forceinline__ unsigned short f2bf(float f) {  // RNE
  u32 u = __builtin_bit_cast(u32, f);
  u += 0x7FFFu + ((u >> 16) & 1u);
  return (unsigned short)(u >> 16);
}
// async 16B/lane global->LDS: lds dst = wave-uniform base + lane*16
__device__ __forceinline__ void load_lds16(const void* g, void* l) {
  __builtin_amdgcn_global_load_lds((const __attribute__((address_space(1))) u32*)g,
                                   (__attribute__((address_space(3))) u32*)l, 16, 0, 0);
}

// Prep (512 blocks): K slab fp32->bf16 (plain [b][key][d]) + V 64-key tile ->
// vt[b][t*4+w][d][32key] bf16 (32-key wave windows, natural key order inside window).
__global__ __launch_bounds__(256) void prep_kv(
    const float* __restrict__ k, const float* __restrict__ v,
    unsigned short* __restrict__ kb, unsigned short* __restrict__ vt) {
  __shared__ float tileT[64 * 68];  // [d][key-in-64]
  const int blk = blockIdx.x, tid = threadIdx.x;
  size_t base = (size_t)blk * 4096 + tid * 4;
#pragma unroll
  for (int i = 0; i < 4; i++) {
    size_t off = base + (size_t)i * 1024;
    floatx4 f = *(const floatx4*)(k + off);
    ushortx4 h;
    h[0] = f2bf(f[0]); h[1] = f2bf(f[1]); h[2] = f2bf(f[2]); h[3] = f2bf(f[3]);
    *(ushortx4*)(kb + off) = h;
  }
  // V: block = (b, h) covering keys [h*64, h*64+64) -> windows (t=h>>1, w=2*(h&1)+s)
  const int b = blk >> 6, h = blk & 63;
  const int r = tid >> 2, c4 = (tid & 3) * 16;
  const float* vp = v + ((size_t)b * 4096 + h * 64 + r) * 64 + c4;
#pragma unroll
  for (int i = 0; i < 4; i++) {
    floatx4 f = *(const floatx4*)(vp + i * 4);
#pragma unroll
    for (int j = 0; j < 4; j++) tileT[(c4 + i * 4 + j) * 68 + r] = f[j];
  }
  __syncthreads();
  const int d = tid >> 2, g = tid & 3;
  unsigned short* vb = vt + (size_t)b * 262144 + ((h >> 1) * 4 + (h & 1) * 2) * 2048;
#pragma unroll
  for (int s = 0; s < 2; s++) {
    const float* src = tileT + d * 68 + s * 32 + g * 8;
    floatx4 f0 = *(const floatx4*)src;
    floatx4 f1 = *(const floatx4*)(src + 4);
    ushortx8 hh;
#pragma unroll
    for (int j = 0; j < 4; j++) { hh[j] = f2bf(f0[j]); hh[4 + j] = f2bf(f1[j]); }
    *(ushortx8*)(vb + s * 2048 + d * 32 + g * 8) = hh;
  }
}

// Attention: 512 blocks x 256 thr (4 waves), barrier-free, software-pipelined —
// EXACT round-0 structure (verified 47us): 32-key wave windows; K staged via DMA
// 2 tiles ahead (4 LDS bufs, row-PERMUTED so two 16-key QK tiles concatenate into
// one K32 PV B-frag); V register ping-pong 1 tile ahead; per-iter wait =
// s_waitcnt vmcnt(12). Ledger of falsified variants: min-waves hints spill (r1-3);
// 32-row Q-tiles double K/V L2 traffic (r4); kf reg-prefetch costs residency (r5,6);
// key-split + VALU-l + mod-3 rotation adds 36 arch VGPR and breaks offset folding
// (r7). SINGLE delta vs round 0: s_setprio(1) around MFMA clusters (m191: attn
// +4-7%; precondition holds — barrier-free, co-resident waves from different
// blocks drift out of phase -> scheduler role diversity).
// S^T=K*Q^T -> C-layout==PV B-frag layout -> P register-direct; l via ones-A K32.
__global__ __launch_bounds__(256) void attn(
    const float* __restrict__ q, const unsigned short* __restrict__ kb,
    const unsigned short* __restrict__ vt, const float* __restrict__ mask,
    float* __restrict__ out) {
  // loop: 4 waves x 4 K bufs x 2048 ushorts = 65536 B (wave-private)
  // epilogue reuses: obuf 2x[64][72] fp32 + lbuf [4][64] = 37888 B
  __shared__ __align__(16) char smem_raw[65536];
  unsigned short* smem = (unsigned short*)smem_raw;
  const int tid = threadIdx.x;
  const int wave = tid >> 6, lane = tid & 63;
  const int c = lane & 15, quad = lane >> 4;
  const int b = blockIdx.x & 7, qt = blockIdx.x >> 3;  // blk%8=batch -> per-XCD L2 locality
  const int q0 = qt * 64;

  const unsigned short* kB = kb + (size_t)b * (4096 * 64);
  const unsigned short* vtB = vt + (size_t)b * 262144;

  // Q B-frags (B[k=d=kc*32+quad*8+j][n=q=c]), loop-invariant; fold (1/8)*log2(e)
  const float qscale = 0.18033688011112042f;
  short8 qf[4][2];
#pragma unroll
  for (int nt = 0; nt < 4; nt++)
#pragma unroll
    for (int kc = 0; kc < 2; kc++) {
      const float* qp = q + ((size_t)b * 4096 + q0 + nt * 16 + c) * 64 + kc * 32 + quad * 8;
      floatx4 f0 = *(const floatx4*)qp;
      floatx4 f1 = *(const floatx4*)(qp + 4);
      short8 s;
#pragma unroll
      for (int j = 0; j < 4; j++) {
        s[j] = (short)f2bf(f0[j] * qscale);
        s[4 + j] = (short)f2bf(f1[j] * qscale);
      }
      qf[nt][kc] = s;
    }

  floatx4 o[4][4], o_l[4];  // O^T[d=mt*16+quad*4+r][q=nt*16+c]; o_l rows all equal l
#pragma unroll
  for (int mt = 0; mt < 4; mt++)
#pragma unroll
    for (int nt = 0; nt < 4; nt++) o[mt][nt] = (floatx4){0.f, 0.f, 0.f, 0.f};
#pragma unroll
  for (int nt = 0; nt < 4; nt++) o_l[nt] = (floatx4){0.f, 0.f, 0.f, 0.f};

  short8 ones8;
#pragma unroll
  for (int j = 0; j < 8; j++) ones8[j] = (short)0x3F80;

  const int r8 = lane >> 3, cs8 = lane & 7;
  const int klane = (r8 >> 2) * 8 + (r8 & 3);  // row-permutation: C row (quad,r) -> key quad*8+r
  unsigned short* wbase = smem + wave * 8192;  // 4 bufs x 2048
  const unsigned short* gK0 = kB + (size_t)(wave * 32 + klane) * 64 + (cs8 ^ r8) * 8;
  const unsigned short* gV0 = vtB + wave * 2048 + c * 32 + quad * 8;

  auto stageK = [&](int t, int buf) {  // 4KB: tileA (keys {q8+0..3}) | tileB ({q8+4..7})
    unsigned short* Kd = wbase + buf * 2048;
    const unsigned short* gk = gK0 + (size_t)t * 8192;
    load_lds16(gk, Kd);                   // tileA rows 0-7   (key off  0)
    load_lds16(gk + 16 * 64, Kd + 512);   // tileA rows 8-15  (key off 16)
    load_lds16(gk + 4 * 64, Kd + 1024);   // tileB rows 0-7   (key off  4)
    load_lds16(gk + 20 * 64, Kd + 1536);  // tileB rows 8-15  (key off 20)
  };
  auto loadV = [&](u32x4* vv, int t) {  // 4 x 1KB-coalesced register loads
    const unsigned short* gv = gV0 + (size_t)t * 8192;
#pragma unroll
    for (int mt = 0; mt < 4; mt++) vv[mt] = *(const u32x4*)(gv + mt * 512);
  };

  auto compute = [&](const unsigned short* Kbuf, const u32x4* vv) {
    short8 kfA[2], kfB[2];  // A[m=key][k=d]; phys slot = (kc*4+quad)^(c&7)
#pragma unroll
    for (int kc = 0; kc < 2; kc++) {
      const int sl = ((kc * 4 + quad) ^ (c & 7)) * 8;
      kfA[kc] = *(const short8*)(Kbuf + c * 64 + sl);
      kfB[kc] = *(const short8*)(Kbuf + 1024 + c * 64 + sl);
    }
#pragma unroll
    for (int nt = 0; nt < 4; nt++) {
      floatx4 sA = (floatx4){0.f, 0.f, 0.f, 0.f}, sB = sA;
      __builtin_amdgcn_s_setprio(1);
      sA = MFMA_K32(kfA[0], qf[nt][0], sA);
      sA = MFMA_K32(kfA[1], qf[nt][1], sA);
      sB = MFMA_K32(kfB[0], qf[nt][0], sB);
      sB = MFMA_K32(kfB[1], qf[nt][1], sB);
      __builtin_amdgcn_s_setprio(0);
      // P^T[key=quad*8+j][q=nt*16+c]: A gives j=0..3, B gives j=4..7 (row-permuted staging)
      u32 a0 = __builtin_bit_cast(u32, EXP2(sA[0]));
      u32 a1 = __builtin_bit_cast(u32, EXP2(sA[1]));
      u32 a2 = __builtin_bit_cast(u32, EXP2(sA[2]));
      u32 a3 = __builtin_bit_cast(u32, EXP2(sA[3]));
      u32 b0 = __builtin_bit_cast(u32, EXP2(sB[0]));
      u32 b1 = __builtin_bit_cast(u32, EXP2(sB[1]));
      u32 b2 = __builtin_bit_cast(u32, EXP2(sB[2]));
      u32 b3 = __builtin_bit_cast(u32, EXP2(sB[3]));
      u32x4 pw = {__builtin_amdgcn_perm(a1, a0, 0x07060302u),
                  __builtin_amdgcn_perm(a3, a2, 0x07060302u),
                  __builtin_amdgcn_perm(b1, b0, 0x07060302u),
                  __builtin_amdgcn_perm(b3, b2, 0x07060302u)};
      short8 pf = __builtin_bit_cast(short8, pw);  // K32 B-frag: B[k=quad*8+j][n=c]
      __builtin_amdgcn_s_setprio(1);
#pragma unroll
      for (int mt = 0; mt < 4; mt++)
        o[mt][nt] = MFMA_K32(__builtin_bit_cast(short8, vv[mt]), pf, o[mt][nt]);
      o_l[nt] = MFMA_K32(ones8, pf, o_l[nt]);  // l rows: Sum_k P^T[k][q]
      __builtin_amdgcn_s_setprio(0);
    }
  };

  u32x4 vvA[4], vvB[4];
  stageK(0, 0);
  loadV(vvA, 0);
  stageK(1, 1);

#pragma unroll 1
  for (int tt = 0; tt < 16; tt++) {
    const int t0 = 2 * tt, t1 = t0 + 1;
    // iter t0: issue V(t0+1), K(t0+2); wait leaves K(t0+1),V(t0+1),K(t0+2) in flight
    loadV(vvB, t1);
    if (t0 + 2 < 32) { stageK(t0 + 2, (t0 + 2) & 3); WAIT_VM12(); }
    else { WAIT_VM8(); }  // t0=30: K31 + V31 outstanding
    SB0();
    compute(wbase + (t0 & 3) * 2048, vvA);
    // iter t1
    if (t1 + 2 < 32) { loadV(vvA, t1 + 1); stageK(t1 + 2, (t1 + 2) & 3); WAIT_VM12(); }
    else { WAIT_VM0(); }  // t1=31
    SB0();
    compute(wbase + (t1 & 3) * 2048, vvB);
  }

  // ---- merge 4 wave-partials (first barriers since loop start) ----
  __syncthreads();
  float* obuf = (float*)smem_raw;  // 2 x [64 q][72]
  float* lbuf = obuf + 9216;       // [4 waves][64 q]
  if (lane < 16) {
#pragma unroll
    for (int nt = 0; nt < 4; nt++) lbuf[wave * 64 + nt * 16 + c] = o_l[nt][0];
  }
  if (wave < 2) {
    float* ob = obuf + wave * 4608;
#pragma unroll
    for (int mt = 0; mt < 4; mt++)
#pragma unroll
      for (int nt = 0; nt < 4; nt++)
        *(floatx4*)(ob + (nt * 16 + c) * 72 + mt * 16 + quad * 4) = o[mt][nt];
  }
  __syncthreads();
  if (wave >= 2) {
    float* ob = obuf + (wave - 2) * 4608;
#pragma unroll
    for (int mt = 0; mt < 4; mt++)
#pragma unroll
      for (int nt = 0; nt < 4; nt++) {
        float* a = ob + (nt * 16 + c) * 72 + mt * 16 + quad * 4;
        floatx4 cur = *(floatx4*)a;
        *(floatx4*)a = cur + o[mt][nt];
      }
  }
  __syncthreads();

  // out = O/l * mask, coalesced float4 stores
  const int row = tid >> 2, dg = (tid & 3) * 16;
  const float l = lbuf[row] + lbuf[64 + row] + lbuf[128 + row] + lbuf[192 + row];
  const float sc = mask[b * 4096 + q0 + row] / l;
  float* op = out + ((size_t)b * 4096 + q0 + row) * 64 + dg;
#pragma unroll
  for (int i = 0; i < 4; i++) {
    floatx4 a = *(const floatx4*)(obuf + row * 72 + dg + i * 4);
    floatx4 b2 = *(const floatx4*)(obuf + 4608 + row * 72 + dg + i * 4);
    *(floatx4*)(op + i * 4) = (a + b2) * sc;
  }
}

extern "C" void kernel_launch(void* const* d_in, const int* in_sizes, int n_in,
                              void* d_out, int out_size, void* d_ws, size_t ws_size,
                              hipStream_t stream) {
  const float* q = (const float*)d_in[0];
  const float* k = (const float*)d_in[1];
  const float* v = (const float*)d_in[2];
  const float* mask = (const float*)d_in[3];
  unsigned short* kb = (unsigned short*)d_ws;  // 4 MB
  unsigned short* vt = kb + 8 * 4096 * 64;     // 4 MB (needs ws >= 8 MB)
  prep_kv<<<512, 256, 0, stream>>>(k, v, kb, vt);
  attn<<<512, 256, 0, stream>>>(q, kb, vt, mask, (float*)d_out);
}